// Round 6
// baseline (1052.270 us; speedup 1.0000x reference)
//
#include <hip/hip_runtime.h>

// 2-layer LSTM (H=128) + FC, round 17: bisect — revert literal-0 MFMA asm.
//
// v15/v16 both failed at ~9e-3 regardless of bias precision -> bias was
// NOT the bug. Shared-delta analysis vs v14 (passing): the only piece
// not verifiable by inspection is the inline-asm MFMA with literal 0 as
// src2 (accumulator). v17 reverts ONLY that: layer-0 first MFMA uses the
// intrinsic with a zero vector (v14-proven), layer-1 uses explicit
// acc={0} + mfma_agpr chain (v14-proven). The v15/v16 register trims are
// KEPT: gate-major wxg records [4][HID][8] with fp32 bias in dword 3,
// one ds_read_b128 per gate in the l0 pointwise, single blds[HID][4].
// If this passes -> literal-0 src2 was the bug. If not -> reorg is next.

#define SEQ    512
#define HID    128
#define NTHR   512
#define NBLK   256

typedef _Float16 half_t;
typedef __attribute__((ext_vector_type(2))) _Float16 half2_t;
typedef __attribute__((ext_vector_type(8))) _Float16 half8_t;
typedef __attribute__((ext_vector_type(4))) float floatx4;

__device__ __forceinline__ half2_t pkrtz(float a, float b) {
    return __builtin_bit_cast(half2_t, __builtin_amdgcn_cvt_pkrtz(a, b));
}
__device__ __forceinline__ half2_t bch2(float f) {
    return __builtin_bit_cast(half2_t, f);
}
__device__ __forceinline__ float dot2f(half2_t a, half2_t b, float c) {
    return __builtin_amdgcn_fdot2(a, b, c, false);
}
__device__ __forceinline__ float sigm(float v) { return 1.0f / (1.0f + __expf(-v)); }
__device__ __forceinline__ float tanh_fast(float v) {
    float e = __expf(2.0f * v);
    return 1.0f - 2.0f / (e + 1.0f);
}
__device__ __forceinline__ float selr(floatx4 v, int r) {
    float a = (r & 1) ? v[1] : v[0];
    float b = (r & 1) ? v[3] : v[2];
    return (r & 2) ? b : a;
}
// MFMA, B in AGPR, accumulate in place (v14-proven).
__device__ __forceinline__ void mfma_agpr(floatx4& c, half8_t a, half8_t b) {
    asm("v_mfma_f32_16x16x32_f16 %0, %1, %2, %0" : "+v"(c) : "v"(a), "a"(b));
}

__global__ void __launch_bounds__(NTHR, 2)
lstm2_v17(const float* __restrict__ x,
          const float* __restrict__ w_ih0, const float* __restrict__ w_hh0,
          const float* __restrict__ b_ih0, const float* __restrict__ b_hh0,
          const float* __restrict__ w_ih1, const float* __restrict__ w_hh1,
          const float* __restrict__ b_ih1, const float* __restrict__ b_hh1,
          const float* __restrict__ fc_w,  const float* __restrict__ fc_b,
          float* __restrict__ out)
{
    const int t   = threadIdx.x;
    const int w   = t >> 6;
    const int l   = t & 63;
    const int m16 = l & 15;
    const int kg  = l >> 4;            // frag k-group; pointwise batch row
    const int jj  = (w << 4) | m16;    // hidden index 0..127
    const int row0 = blockIdx.x * 4;

    __shared__ __align__(16) half2_t xs2[SEQ][4][4];    // 32 KB
    __shared__ __align__(16) half_t  h1t[2][4][64][8];  // 8 KB frag-order
    __shared__ __align__(16) half_t  h2t[2][4][64][8];  // 8 KB
    __shared__ __align__(16) half_t  wxg[4][HID][8];    // 8 KB: (w01,w23,(w4,0),b0f32)
    __shared__ __align__(16) float   blds[HID][4];      // 2 KB bias1
    __shared__ float wpart[8][4];

    // ---- stationary weight fragments ----
    half8_t bf0[4][4];                 // w_hh0: VGPR (intrinsic MFMA)
    half8_t bf1[8][4];                 // [w_ih1|w_hh1]: AGPR ("a" asm MFMA)
#pragma unroll
    for (int kt = 0; kt < 4; ++kt)
#pragma unroll
        for (int nt = 0; nt < 4; ++nt) {
            const float* p = w_hh0 + (size_t)(nt * HID + jj) * HID + kt * 32 + kg * 8;
            float4 a = *(const float4*)p;
            float4 b = *(const float4*)(p + 4);
            half8_t v;
            v[0]=(half_t)a.x; v[1]=(half_t)a.y; v[2]=(half_t)a.z; v[3]=(half_t)a.w;
            v[4]=(half_t)b.x; v[5]=(half_t)b.y; v[6]=(half_t)b.z; v[7]=(half_t)b.w;
            bf0[kt][nt] = v;
        }
#pragma unroll
    for (int kt = 0; kt < 8; ++kt) {
        const float* W = (kt < 4) ? w_ih1 : w_hh1;
        const int kc = (kt & 3) * 32;
#pragma unroll
        for (int nt = 0; nt < 4; ++nt) {
            const float* p = W + (size_t)(nt * HID + jj) * HID + kc + kg * 8;
            float4 a = *(const float4*)p;
            float4 b = *(const float4*)(p + 4);
            half8_t v;
            v[0]=(half_t)a.x; v[1]=(half_t)a.y; v[2]=(half_t)a.z; v[3]=(half_t)a.w;
            v[4]=(half_t)b.x; v[5]=(half_t)b.y; v[6]=(half_t)b.z; v[7]=(half_t)b.w;
            bf1[kt][nt] = v;
        }
    }

    // ---- one-time preloads ----
    for (int i = t; i < SEQ * 4; i += NTHR) {          // x -> packed half2 LDS
        int s = i >> 2, r = i & 3;
        const float* p = x + (size_t)(row0 + r) * (SEQ * 5) + s * 5;
        half2_t* d = &xs2[s][r][0];
        d[0] = pkrtz(p[0], p[1]);
        d[1] = pkrtz(p[2], p[3]);
        d[2] = pkrtz(p[4], 0.0f);      // pad slot (matches v14 exactly)
    }
    if (t < HID) {                                     // l0 x-weights + fp32 bias0
#pragma unroll
        for (int g = 0; g < 4; ++g) {
            const float* p = w_ih0 + (g * HID + t) * 5;
            float b0 = b_ih0[g * HID + t] + b_hh0[g * HID + t];
            half2_t* d = (half2_t*)&wxg[g][t][0];
            d[0] = pkrtz(p[0], p[1]);
            d[1] = pkrtz(p[2], p[3]);
            d[2] = pkrtz(p[4], 0.0f);  // fp16 weights only
            ((float*)d)[3] = b0;       // RAW FP32 bias in dword 3
        }
#pragma unroll
        for (int nt = 0; nt < 4; ++nt)                 // bias1 -> LDS (fp32)
            blds[t][nt] = b_ih1[nt * HID + t] + b_hh1[nt * HID + t];
    }
    for (int i = t; i < 4096; i += NTHR) {
        ((half_t*)h1t)[i] = (half_t)0;
        ((half_t*)h2t)[i] = (half_t)0;
    }
    const int kts  = jj >> 5;
    const int slot = (jj >> 3) & 3;
    const int je   = jj & 7;
    float c1 = 0.0f, c2 = 0.0f, h2v = 0.0f;
    __syncthreads();

    // ================= FUSED LOOP: l0 step s + l1 step s-1 =================
#pragma unroll 1
    for (int s = 0; s <= SEQ; ++s) {
        const int pb = s & 1, nb = pb ^ 1;
        const half_t* h1r = &h1t[pb][0][l][0];   // kt stride = 512 halves
        const half_t* h2r = &h2t[pb][0][l][0];

        floatx4 acc[4];
        const floatx4 zf = (floatx4){0.f, 0.f, 0.f, 0.f};
        // ---- layer-0 recurrence GEMM (K=128), 2-slot A-frag rotation ----
        half8_t f0 = *(const half8_t*)(h1r);
        half8_t f1 = *(const half8_t*)(h1r + 512);
#pragma unroll
        for (int nt = 0; nt < 4; ++nt)
            acc[nt] = __builtin_amdgcn_mfma_f32_16x16x32_f16(f0, bf0[0][nt], zf, 0, 0, 0);
        f0 = *(const half8_t*)(h1r + 1024);
#pragma unroll
        for (int nt = 0; nt < 4; ++nt)
            acc[nt] = __builtin_amdgcn_mfma_f32_16x16x32_f16(f1, bf0[1][nt], acc[nt], 0, 0, 0);
        f1 = *(const half8_t*)(h1r + 1536);
#pragma unroll
        for (int nt = 0; nt < 4; ++nt)
            acc[nt] = __builtin_amdgcn_mfma_f32_16x16x32_f16(f0, bf0[2][nt], acc[nt], 0, 0, 0);
#pragma unroll
        for (int nt = 0; nt < 4; ++nt)
            acc[nt] = __builtin_amdgcn_mfma_f32_16x16x32_f16(f1, bf0[3][nt], acc[nt], 0, 0, 0);

        // ---- layer-0 pointwise: acc dies here ----
        if (s < SEQ) {
            int zoff;                               // opaque 0: defeat LICM
            asm volatile("v_mov_b32 %0, 0" : "=v"(zoff));
            float4 xv = *(const float4*)((const char*)&xs2[s][kg][0] + zoff);
            half2_t x01 = bch2(xv.x), x23 = bch2(xv.y), x4z = bch2(xv.z);
            float gv4[4];
#pragma unroll
            for (int g = 0; g < 4; ++g) {           // one b128 per gate
                float4 wv = *(const float4*)((const char*)&wxg[g][jj][0] + zoff);
                gv4[g] = selr(acc[g], kg) + wv.w    // fp32 bias0
                       + dot2f(x4z, bch2(wv.z), dot2f(x23, bch2(wv.y), dot2f(x01, bch2(wv.x), 0.f)));
            }
            float iv = sigm(gv4[0]), fv = sigm(gv4[1]);
            float gg = tanh_fast(gv4[2]), ov = sigm(gv4[3]);
            c1 = fmaf(fv, c1, iv * gg);
            half_t hh = (half_t)(ov * tanh_fast(c1));
#pragma unroll
            for (int a2 = 0; a2 < 4; ++a2)
                h1t[nb][kts][slot * 16 + kg + 4 * a2][je] = hh;   // M-replication
        }
        // pin: l1 MFMAs stay below the l0 pointwise (single live acc gen);
        // DS reads may still hoist for latency hiding.
        __builtin_amdgcn_sched_barrier(0x100);

        // ---- layer-1 GEMM (K=256 concat), B from AGPR, reuses acc ----
#pragma unroll
        for (int nt = 0; nt < 4; ++nt)
            acc[nt] = (floatx4){0.f, 0.f, 0.f, 0.f};
        f0 = *(const half8_t*)(h1r);
        f1 = *(const half8_t*)(h1r + 512);
#pragma unroll
        for (int nt = 0; nt < 4; ++nt) mfma_agpr(acc[nt], f0, bf1[0][nt]);
        f0 = *(const half8_t*)(h1r + 1024);
#pragma unroll
        for (int nt = 0; nt < 4; ++nt) mfma_agpr(acc[nt], f1, bf1[1][nt]);
        f1 = *(const half8_t*)(h1r + 1536);
#pragma unroll
        for (int nt = 0; nt < 4; ++nt) mfma_agpr(acc[nt], f0, bf1[2][nt]);
        f0 = *(const half8_t*)(h2r);
#pragma unroll
        for (int nt = 0; nt < 4; ++nt) mfma_agpr(acc[nt], f1, bf1[3][nt]);
        f1 = *(const half8_t*)(h2r + 512);
#pragma unroll
        for (int nt = 0; nt < 4; ++nt) mfma_agpr(acc[nt], f0, bf1[4][nt]);
        f0 = *(const half8_t*)(h2r + 1024);
#pragma unroll
        for (int nt = 0; nt < 4; ++nt) mfma_agpr(acc[nt], f1, bf1[5][nt]);
        f1 = *(const half8_t*)(h2r + 1536);
#pragma unroll
        for (int nt = 0; nt < 4; ++nt) mfma_agpr(acc[nt], f0, bf1[6][nt]);
#pragma unroll
        for (int nt = 0; nt < 4; ++nt) mfma_agpr(acc[nt], f1, bf1[7][nt]);

        // ---- layer-1 pointwise (step s-1) ----
        if (s > 0) {
            int z1;
            asm volatile("v_mov_b32 %0, 0" : "=v"(z1));
            float4 bv1 = *(const float4*)((const char*)&blds[jj][0] + z1);
            float gi = selr(acc[0], kg) + bv1.x;
            float gf = selr(acc[1], kg) + bv1.y;
            float gg = selr(acc[2], kg) + bv1.z;
            float go = selr(acc[3], kg) + bv1.w;
            float iv = sigm(gi), fv = sigm(gf), gv = tanh_fast(gg), ov = sigm(go);
            c2 = fmaf(fv, c2, iv * gv);
            h2v = ov * tanh_fast(c2);
            half_t hh = (half_t)h2v;
#pragma unroll
            for (int a2 = 0; a2 < 4; ++a2)
                h2t[nb][kts][slot * 16 + kg + 4 * a2][je] = hh;
        }
        __syncthreads();
    }

    // ---- epilogue: out[row] = fc_b + sum_j fc_w[j] * h2[511][row][j] ----
    float p = fc_w[jj] * h2v;                        // lane = (row kg, col jj)
    p += __shfl_xor(p, 1);
    p += __shfl_xor(p, 2);
    p += __shfl_xor(p, 4);
    p += __shfl_xor(p, 8);
    if (m16 == 0) wpart[w][kg] = p;
    __syncthreads();
    if (t < 4) {
        float ssum = fc_b[0];
#pragma unroll
        for (int wv = 0; wv < 8; ++wv) ssum += wpart[wv][t];
        out[row0 + t] = ssum;
    }
}

extern "C" void kernel_launch(void* const* d_in, const int* in_sizes, int n_in,
                              void* d_out, int out_size, void* d_ws, size_t ws_size,
                              hipStream_t stream) {
    (void)in_sizes; (void)n_in; (void)ws_size; (void)out_size; (void)d_ws;
    const float* x     = (const float*)d_in[0];
    const float* w_ih0 = (const float*)d_in[1];
    const float* w_hh0 = (const float*)d_in[2];
    const float* b_ih0 = (const float*)d_in[3];
    const float* b_hh0 = (const float*)d_in[4];
    const float* w_ih1 = (const float*)d_in[5];
    const float* w_hh1 = (const float*)d_in[6];
    const float* b_ih1 = (const float*)d_in[7];
    const float* b_hh1 = (const float*)d_in[8];
    const float* fc_w  = (const float*)d_in[9];
    const float* fc_b  = (const float*)d_in[10];
    float* out = (float*)d_out;

    lstm2_v17<<<NBLK, NTHR, 0, stream>>>(x, w_ih0, w_hh0, b_ih0, b_hh0,
                                         w_ih1, w_hh1, b_ih1, b_hh1,
                                         fc_w, fc_b, out);
}

// Round 8
// 997.711 us; speedup vs baseline: 1.0547x; 1.0547x over previous
//
#include <hip/hip_runtime.h>

// 2-layer LSTM (H=128) + FC, round 18 RESUBMIT (r7): infra failure last
// round ("container failed twice") — no counters, no verdict. Kernel
// unchanged from r6 submission.
//
// v17 post-mortem: literal-0 MFMA src2 asm was the correctness bug
// (v17 passes without it). Perf model revision: WRITE_SIZE ~123 MB is
// ~940 B/thread TOTAL = prologue spill of weight-conversion temporaries
// (one-time, ~40 us), NOT per-step loop spill (per-step reloads would
// inflate FETCH by ~250KB/block/step; FETCH is legit at ~70MB). The real
// per-step cost includes ~1700 cy/step/CU of LDS issue, 4x of it wasted:
// M-replicated h-tiles deliver 1024 B/ds_read_b128 with only 256 B
// distinct, plus 4 replicated ds_write_b16 per layer per thread.
// v18 = v14 (best passing base, 932 us) + ONE change: h1t/h2t stored
// un-replicated as [4 rows][144 halfs] (288 B row stride -> row-to-row
// bank shift of 8 banks). A-frag reads alias by address: lane l reads
// row l&3, byte off kt*64 + (l>>4)*16. Per 32-lane phase: 8 distinct
// 16B addresses covering all 32 banks once, 4-way same-address broadcast
// (free). Data per lane is bit-identical to the replicated path
// (both deliver h[l&3][kt*32+(l>>4)*8+e]). Writes: ONE ds_write_b16 per
// layer per thread instead of 4.

#define SEQ    512
#define HID    128
#define NTHR   512
#define NBLK   256
#define HPAD   144                    // h-tile row stride in halfs (288 B)

typedef _Float16 half_t;
typedef __attribute__((ext_vector_type(2))) _Float16 half2_t;
typedef __attribute__((ext_vector_type(8))) _Float16 half8_t;
typedef __attribute__((ext_vector_type(4))) float floatx4;

__device__ __forceinline__ half2_t pkrtz(float a, float b) {
    return __builtin_bit_cast(half2_t, __builtin_amdgcn_cvt_pkrtz(a, b));
}
__device__ __forceinline__ half2_t bch2(float f) {
    return __builtin_bit_cast(half2_t, f);
}
__device__ __forceinline__ float dot2f(half2_t a, half2_t b, float c) {
    return __builtin_amdgcn_fdot2(a, b, c, false);
}
__device__ __forceinline__ float sigm(float v) { return 1.0f / (1.0f + __expf(-v)); }
__device__ __forceinline__ float tanh_fast(float v) {
    float e = __expf(2.0f * v);
    return 1.0f - 2.0f / (e + 1.0f);
}
__device__ __forceinline__ float selr(floatx4 v, int r) {
    float a = (r & 1) ? v[1] : v[0];
    float b = (r & 1) ? v[3] : v[2];
    return (r & 2) ? b : a;
}
// MFMA, B in AGPR, accumulate in place (v14-proven).
__device__ __forceinline__ void mfma_agpr(floatx4& c, half8_t a, half8_t b) {
    asm("v_mfma_f32_16x16x32_f16 %0, %1, %2, %0" : "+v"(c) : "v"(a), "a"(b));
}

__global__ void __launch_bounds__(NTHR, 2)
lstm2_v18(const float* __restrict__ x,
          const float* __restrict__ w_ih0, const float* __restrict__ w_hh0,
          const float* __restrict__ b_ih0, const float* __restrict__ b_hh0,
          const float* __restrict__ w_ih1, const float* __restrict__ w_hh1,
          const float* __restrict__ b_ih1, const float* __restrict__ b_hh1,
          const float* __restrict__ fc_w,  const float* __restrict__ fc_b,
          float* __restrict__ out)
{
    const int t   = threadIdx.x;
    const int w   = t >> 6;
    const int l   = t & 63;
    const int m16 = l & 15;
    const int kg  = l >> 4;            // frag k-group; pointwise batch row
    const int jj  = (w << 4) | m16;    // hidden index 0..127
    const int row0 = blockIdx.x * 4;

    __shared__ __align__(16) half2_t xs2[SEQ][4][4];    // 32 KB
    __shared__ __align__(16) half_t  h1t[2][4][HPAD];   // 2.25 KB, un-replicated
    __shared__ __align__(16) half_t  h2t[2][4][HPAD];   // 2.25 KB
    __shared__ __align__(16) half2_t wxh_lds[HID][12];  // 6 KB l0 x-weights
    __shared__ __align__(16) float   blds[2][HID][4];   // 4 KB biases
    __shared__ float wpart[8][4];

    // ---- stationary weight fragments ----
    half8_t bf0[4][4];                 // w_hh0: VGPR (intrinsic MFMA)
    half8_t bf1[8][4];                 // [w_ih1|w_hh1]: AGPR ("a" asm MFMA)
#pragma unroll
    for (int kt = 0; kt < 4; ++kt)
#pragma unroll
        for (int nt = 0; nt < 4; ++nt) {
            const float* p = w_hh0 + (size_t)(nt * HID + jj) * HID + kt * 32 + kg * 8;
            float4 a = *(const float4*)p;
            float4 b = *(const float4*)(p + 4);
            half8_t v;
            v[0]=(half_t)a.x; v[1]=(half_t)a.y; v[2]=(half_t)a.z; v[3]=(half_t)a.w;
            v[4]=(half_t)b.x; v[5]=(half_t)b.y; v[6]=(half_t)b.z; v[7]=(half_t)b.w;
            bf0[kt][nt] = v;
        }
#pragma unroll
    for (int kt = 0; kt < 8; ++kt) {
        const float* W = (kt < 4) ? w_ih1 : w_hh1;
        const int kc = (kt & 3) * 32;
#pragma unroll
        for (int nt = 0; nt < 4; ++nt) {
            const float* p = W + (size_t)(nt * HID + jj) * HID + kc + kg * 8;
            float4 a = *(const float4*)p;
            float4 b = *(const float4*)(p + 4);
            half8_t v;
            v[0]=(half_t)a.x; v[1]=(half_t)a.y; v[2]=(half_t)a.z; v[3]=(half_t)a.w;
            v[4]=(half_t)b.x; v[5]=(half_t)b.y; v[6]=(half_t)b.z; v[7]=(half_t)b.w;
            bf1[kt][nt] = v;
        }
    }

    // ---- one-time preloads ----
    for (int i = t; i < SEQ * 4; i += NTHR) {          // x -> packed half2 LDS
        int s = i >> 2, r = i & 3;
        const float* p = x + (size_t)(row0 + r) * (SEQ * 5) + s * 5;
        half2_t* d = &xs2[s][r][0];
        d[0] = pkrtz(p[0], p[1]);
        d[1] = pkrtz(p[2], p[3]);
        d[2] = pkrtz(p[4], 0.0f);
    }
    if (t < HID) {                                     // l0 x-weights -> LDS
#pragma unroll
        for (int nt = 0; nt < 4; ++nt) {
            const float* p = w_ih0 + (nt * HID + t) * 5;
            wxh_lds[t][nt * 3 + 0] = pkrtz(p[0], p[1]);
            wxh_lds[t][nt * 3 + 1] = pkrtz(p[2], p[3]);
            wxh_lds[t][nt * 3 + 2] = pkrtz(p[4], 0.0f);
        }
#pragma unroll
        for (int nt = 0; nt < 4; ++nt) {               // biases -> LDS
            blds[0][t][nt] = b_ih0[nt * HID + t] + b_hh0[nt * HID + t];
            blds[1][t][nt] = b_ih1[nt * HID + t] + b_hh1[nt * HID + t];
        }
    }
    for (int i = t; i < 2 * 4 * HPAD; i += NTHR) {     // zero h tiles (incl pad)
        ((half_t*)h1t)[i] = (half_t)0;
        ((half_t*)h2t)[i] = (half_t)0;
    }
    float c1 = 0.0f, c2 = 0.0f, h2v = 0.0f;
    // aliased A-frag read coords: lane l reads row l&3, halfword offset
    // (l>>4)*8 within each kt*32 slice.
    const int arow = l & 3;
    const int aoff = (l >> 4) * 8;
    __syncthreads();

    // ================= FUSED LOOP: l0 step s + l1 step s-1 =================
#pragma unroll 1
    for (int s = 0; s <= SEQ; ++s) {
        const int pb = s & 1, nb = pb ^ 1;
        const half_t* h1r = &h1t[pb][arow][aoff];   // + kt*32 per frag
        const half_t* h2r = &h2t[pb][arow][aoff];

        floatx4 acc[4];
        const floatx4 zf = (floatx4){0.f, 0.f, 0.f, 0.f};
        // ---- layer-0 recurrence GEMM (K=128), 2-slot A-frag rotation ----
        half8_t f0 = *(const half8_t*)(h1r);
        half8_t f1 = *(const half8_t*)(h1r + 32);
#pragma unroll
        for (int nt = 0; nt < 4; ++nt)
            acc[nt] = __builtin_amdgcn_mfma_f32_16x16x32_f16(f0, bf0[0][nt], zf, 0, 0, 0);
        f0 = *(const half8_t*)(h1r + 64);
#pragma unroll
        for (int nt = 0; nt < 4; ++nt)
            acc[nt] = __builtin_amdgcn_mfma_f32_16x16x32_f16(f1, bf0[1][nt], acc[nt], 0, 0, 0);
        f1 = *(const half8_t*)(h1r + 96);
#pragma unroll
        for (int nt = 0; nt < 4; ++nt)
            acc[nt] = __builtin_amdgcn_mfma_f32_16x16x32_f16(f0, bf0[2][nt], acc[nt], 0, 0, 0);
#pragma unroll
        for (int nt = 0; nt < 4; ++nt)
            acc[nt] = __builtin_amdgcn_mfma_f32_16x16x32_f16(f1, bf0[3][nt], acc[nt], 0, 0, 0);

        // ---- layer-0 pointwise: acc dies here ----
        if (s < SEQ) {
            int zoff;                               // opaque 0: defeat LICM
            asm volatile("v_mov_b32 %0, 0" : "=v"(zoff));
            const char* wxb = (const char*)&wxh_lds[jj][0] + zoff;
            float4 wv0 = *(const float4*)(wxb);
            float4 wv1 = *(const float4*)(wxb + 16);
            float4 wv2 = *(const float4*)(wxb + 32);
            float4 bv0 = *(const float4*)((const char*)&blds[0][jj][0] + zoff);
            float4 xv  = *(const float4*)&xs2[s][kg][0];
            half2_t x01 = bch2(xv.x), x23 = bch2(xv.y), x4z = bch2(xv.z);
            float gi = selr(acc[0], kg) + bv0.x + dot2f(x4z, bch2(wv0.z), dot2f(x23, bch2(wv0.y), dot2f(x01, bch2(wv0.x), 0.f)));
            float gf = selr(acc[1], kg) + bv0.y + dot2f(x4z, bch2(wv1.y), dot2f(x23, bch2(wv1.x), dot2f(x01, bch2(wv0.w), 0.f)));
            float gg = selr(acc[2], kg) + bv0.z + dot2f(x4z, bch2(wv2.x), dot2f(x23, bch2(wv1.w), dot2f(x01, bch2(wv1.z), 0.f)));
            float go = selr(acc[3], kg) + bv0.w + dot2f(x4z, bch2(wv2.w), dot2f(x23, bch2(wv2.z), dot2f(x01, bch2(wv2.y), 0.f)));
            float iv = sigm(gi), fv = sigm(gf), gv = tanh_fast(gg), ov = sigm(go);
            c1 = fmaf(fv, c1, iv * gv);
            half_t hh = (half_t)(ov * tanh_fast(c1));
            h1t[nb][kg][jj] = hh;                   // single un-replicated write
        }
        // pin: l1 MFMAs stay below the l0 pointwise (single live acc gen);
        // DS reads may still hoist for latency hiding.
        __builtin_amdgcn_sched_barrier(0x100);

        // ---- layer-1 GEMM (K=256 concat), B from AGPR, reuses acc ----
#pragma unroll
        for (int nt = 0; nt < 4; ++nt)
            acc[nt] = (floatx4){0.f, 0.f, 0.f, 0.f};
        f0 = *(const half8_t*)(h1r);
        f1 = *(const half8_t*)(h1r + 32);
#pragma unroll
        for (int nt = 0; nt < 4; ++nt) mfma_agpr(acc[nt], f0, bf1[0][nt]);
        f0 = *(const half8_t*)(h1r + 64);
#pragma unroll
        for (int nt = 0; nt < 4; ++nt) mfma_agpr(acc[nt], f1, bf1[1][nt]);
        f1 = *(const half8_t*)(h1r + 96);
#pragma unroll
        for (int nt = 0; nt < 4; ++nt) mfma_agpr(acc[nt], f0, bf1[2][nt]);
        f0 = *(const half8_t*)(h2r);
#pragma unroll
        for (int nt = 0; nt < 4; ++nt) mfma_agpr(acc[nt], f1, bf1[3][nt]);
        f1 = *(const half8_t*)(h2r + 32);
#pragma unroll
        for (int nt = 0; nt < 4; ++nt) mfma_agpr(acc[nt], f0, bf1[4][nt]);
        f0 = *(const half8_t*)(h2r + 64);
#pragma unroll
        for (int nt = 0; nt < 4; ++nt) mfma_agpr(acc[nt], f1, bf1[5][nt]);
        f1 = *(const half8_t*)(h2r + 96);
#pragma unroll
        for (int nt = 0; nt < 4; ++nt) mfma_agpr(acc[nt], f0, bf1[6][nt]);
#pragma unroll
        for (int nt = 0; nt < 4; ++nt) mfma_agpr(acc[nt], f1, bf1[7][nt]);

        // ---- layer-1 pointwise (step s-1) ----
        if (s > 0) {
            int z1;
            asm volatile("v_mov_b32 %0, 0" : "=v"(z1));
            float4 bv1 = *(const float4*)((const char*)&blds[1][jj][0] + z1);
            float gi = selr(acc[0], kg) + bv1.x;
            float gf = selr(acc[1], kg) + bv1.y;
            float gg = selr(acc[2], kg) + bv1.z;
            float go = selr(acc[3], kg) + bv1.w;
            float iv = sigm(gi), fv = sigm(gf), gv = tanh_fast(gg), ov = sigm(go);
            c2 = fmaf(fv, c2, iv * gv);
            h2v = ov * tanh_fast(c2);
            h2t[nb][kg][jj] = (half_t)h2v;          // single un-replicated write
        }
        __syncthreads();
    }

    // ---- epilogue: out[row] = fc_b + sum_j fc_w[j] * h2[511][row][j] ----
    float p = fc_w[jj] * h2v;                        // lane = (row kg, col jj)
    p += __shfl_xor(p, 1);
    p += __shfl_xor(p, 2);
    p += __shfl_xor(p, 4);
    p += __shfl_xor(p, 8);
    if (m16 == 0) wpart[w][kg] = p;
    __syncthreads();
    if (t < 4) {
        float ssum = fc_b[0];
#pragma unroll
        for (int wv = 0; wv < 8; ++wv) ssum += wpart[wv][t];
        out[row0 + t] = ssum;
    }
}

extern "C" void kernel_launch(void* const* d_in, const int* in_sizes, int n_in,
                              void* d_out, int out_size, void* d_ws, size_t ws_size,
                              hipStream_t stream) {
    (void)in_sizes; (void)n_in; (void)ws_size; (void)out_size; (void)d_ws;
    const float* x     = (const float*)d_in[0];
    const float* w_ih0 = (const float*)d_in[1];
    const float* w_hh0 = (const float*)d_in[2];
    const float* b_ih0 = (const float*)d_in[3];
    const float* b_hh0 = (const float*)d_in[4];
    const float* w_ih1 = (const float*)d_in[5];
    const float* w_hh1 = (const float*)d_in[6];
    const float* b_ih1 = (const float*)d_in[7];
    const float* b_hh1 = (const float*)d_in[8];
    const float* fc_w  = (const float*)d_in[9];
    const float* fc_b  = (const float*)d_in[10];
    float* out = (float*)d_out;

    lstm2_v18<<<NBLK, NTHR, 0, stream>>>(x, w_ih0, w_hh0, b_ih0, b_hh0,
                                         w_ih1, w_hh1, b_ih1, b_hh1,
                                         fc_w, fc_b, out);
}